// Round 2
// baseline (318.471 us; speedup 1.0000x reference)
//
#include <hip/hip_runtime.h>
#include <hip/hip_cooperative_groups.h>

namespace cg = cooperative_groups;

#define SS 2048
#define EE 1024
#define NH 16
#define DH 64
#define NR 128    // max stored segment rows (true count ~Binomial(2048,1/32), mean 64)
#define GB 512    // cooperative grid; __launch_bounds__(256,4) guarantees residency

// ---- workspace layout (bytes) ----
// 0      : float xsum[1024]
// 4096   : float vtot[1024]
// 8192   : float A[1024]      (attention numerator sum, atomic)   } memset
// 12288  : float Bh[16]       (sum em/denom per head, atomic)     } 8 KB
// 12352  : int   meta[4]      (0: SS-lo via atomicMax, 1: hi_excl)} zeroed
// 32768  : float xpart[64][1024]  (256 KB, non-atomic partials)
// 294912 : float Q[nmax*1024]; K[...]; V[...]

__device__ __forceinline__ void fma4v(float4& a, const float4 xv,
                                      const float4 w0, const float4 w1,
                                      const float4 w2, const float4 w3) {
    a.x += xv.x * w0.x + xv.y * w1.x + xv.z * w2.x + xv.w * w3.x;
    a.y += xv.x * w0.y + xv.y * w1.y + xv.z * w2.y + xv.w * w3.y;
    a.z += xv.x * w0.z + xv.y * w1.z + xv.z * w2.z + xv.w * w3.z;
    a.w += xv.x * w0.w + xv.y * w1.w + xv.z * w2.w + xv.w * w3.w;
}

__device__ __forceinline__ void lgkm_wait() {
    asm volatile("s_waitcnt lgkmcnt(0)" ::: "memory");
}

__global__ void __launch_bounds__(256, 4) mega(
    const float* __restrict__ x, const int* __restrict__ seg,
    const int* __restrict__ pos,
    const float* __restrict__ Wq, const float* __restrict__ bq,
    const float* __restrict__ Wk, const float* __restrict__ bk,
    const float* __restrict__ Wv, const float* __restrict__ bv,
    const float* __restrict__ Wo, const float* __restrict__ bo,
    float* __restrict__ xsum, float* __restrict__ vtot,
    float* __restrict__ A, float* __restrict__ Bh,
    int* __restrict__ meta, float* __restrict__ xpart,
    float* __restrict__ Q, float* __restrict__ K, float* __restrict__ V,
    int nmax, int phase, float* __restrict__ out) {
    __shared__ float lds[4096];          // 16 KB, re-used per phase
    const int t = threadIdx.x;
    const int bid = blockIdx.x;
    const int gb = gridDim.x;
    const int wv = t >> 6;
    const int lane = t & 63;

    // ================= phase 0: x column-sum partials + segment bounds =====
    if (phase < 0 || phase == 0) {
        for (int it = bid; it < 72; it += gb) {
            if (it < 64) {               // 64 blocks x 32 rows -> xpart[it][*]
                const float4* x4 = (const float4*)x + (size_t)(it * 32) * 256 + t;
                float4 a = make_float4(0.f, 0.f, 0.f, 0.f);
#pragma unroll 8
                for (int r = 0; r < 32; ++r) {
                    float4 v = x4[(size_t)r * 256];
                    a.x += v.x; a.y += v.y; a.z += v.z; a.w += v.w;
                }
                ((float4*)(xpart + (size_t)it * EE))[t] = a;
            } else {                     // 8 blocks: segment bounds
                int i = (it - 64) * 256 + t;
                int g = seg[pos[0]];
                if (seg[i] == g) {
                    atomicMax(&meta[0], SS - i);
                    atomicMax(&meta[1], i + 1);
                }
            }
        }
    }
    if (phase < 0) cg::this_grid().sync();

    // ================= phase 1: Q/K/V projection + xsum reduce =============
    if (phase < 0 || phase == 1) {
        int lo = SS - __builtin_amdgcn_readfirstlane(meta[0]);
        int nc = __builtin_amdgcn_readfirstlane(meta[1]) - lo;
        if (nc > nmax) nc = nmax; if (nc < 1) nc = 1;
        for (int it = bid; it < 400; it += gb) {
            if (it < 384) {              // proj tile: (mat, rowTile, colTile)
                int ct = it & 3, rt = (it >> 2) & 31, mat = it >> 7;
                int r0 = rt * 4;
                if (r0 < nc) {           // runtime-uniform per block
                    const float* W  = mat == 0 ? Wq : mat == 1 ? Wk : Wv;
                    const float* bb = mat == 0 ? bq : mat == 1 ? bk : bv;
                    float* dst      = mat == 0 ? Q  : mat == 1 ? K  : V;
                    int e0 = ct * 256 + lane * 4;
                    int r1 = r0 + 1 < nc ? r0 + 1 : nc - 1;   // clamp; discarded
                    int r2 = r0 + 2 < nc ? r0 + 2 : nc - 1;
                    int r3 = r0 + 3 < nc ? r0 + 3 : nc - 1;
                    const float* xb  = x + (size_t)lo * EE + wv * 256;
                    const float* x0p = xb + (size_t)r0 * EE;
                    const float* x1p = xb + (size_t)r1 * EE;
                    const float* x2p = xb + (size_t)r2 * EE;
                    const float* x3p = xb + (size_t)r3 * EE;
                    const float* Wp = W + (size_t)(wv * 256) * EE + e0;
                    float4 a0 = make_float4(0.f, 0.f, 0.f, 0.f);
                    float4 a1 = a0, a2 = a0, a3 = a0;
#pragma unroll 2
                    for (int c = 0; c < 256; c += 4) {
                        float4 w0 = *(const float4*)(Wp + (size_t)(c + 0) * EE);
                        float4 w1 = *(const float4*)(Wp + (size_t)(c + 1) * EE);
                        float4 w2 = *(const float4*)(Wp + (size_t)(c + 2) * EE);
                        float4 w3 = *(const float4*)(Wp + (size_t)(c + 3) * EE);
                        float4 xv0 = *(const float4*)(x0p + c);
                        float4 xv1 = *(const float4*)(x1p + c);
                        float4 xv2 = *(const float4*)(x2p + c);
                        float4 xv3 = *(const float4*)(x3p + c);
                        fma4v(a0, xv0, w0, w1, w2, w3);
                        fma4v(a1, xv1, w0, w1, w2, w3);
                        fma4v(a2, xv2, w0, w1, w2, w3);
                        fma4v(a3, xv3, w0, w1, w2, w3);
                    }
                    __syncthreads();     // LDS reuse guard (grid-stride safety)
                    *(float4*)(lds + ((wv << 2) + 0) * 256 + (lane << 2)) = a0;
                    *(float4*)(lds + ((wv << 2) + 1) * 256 + (lane << 2)) = a1;
                    *(float4*)(lds + ((wv << 2) + 2) * 256 + (lane << 2)) = a2;
                    *(float4*)(lds + ((wv << 2) + 3) * 256 + (lane << 2)) = a3;
                    __syncthreads();
                    // reduce 4 K-chunk partials: thread -> (row=wv, col4=lane*4)
                    int oc = lane << 2;
                    float4 s0 = *(float4*)(lds + (0 * 4 + wv) * 256 + oc);
                    float4 s1 = *(float4*)(lds + (1 * 4 + wv) * 256 + oc);
                    float4 s2 = *(float4*)(lds + (2 * 4 + wv) * 256 + oc);
                    float4 s3 = *(float4*)(lds + (3 * 4 + wv) * 256 + oc);
                    float4 bbv = *(const float4*)(bb + ct * 256 + oc);
                    float4 s;
                    s.x = s0.x + s1.x + s2.x + s3.x + bbv.x;
                    s.y = s0.y + s1.y + s2.y + s3.y + bbv.y;
                    s.z = s0.z + s1.z + s2.z + s3.z + bbv.z;
                    s.w = s0.w + s1.w + s2.w + s3.w + bbv.w;
                    int gr = r0 + wv;
                    if (gr < nc)
                        *(float4*)(dst + (size_t)gr * EE + ct * 256 + oc) = s;
                    __syncthreads();
                }
            } else {                     // 16 blocks: xsum[c] = sum_b xpart[b][c]
                int c0 = (it - 384) * 64;
                float a = 0.f;
                for (int b = wv; b < 64; b += 4)
                    a += xpart[(size_t)b * EE + c0 + lane];
                __syncthreads();
                lds[t] = a;
                __syncthreads();
                if (wv == 0)
                    xsum[c0 + lane] = lds[lane] + lds[64 + lane] +
                                      lds[128 + lane] + lds[192 + lane];
                __syncthreads();
            }
        }
    }
    if (phase < 0) cg::this_grid().sync();

    // ================= phase 2: vtot GEMV (blocks 0-3) + attention =========
    if (phase < 0 || phase == 2) {
        int lo = SS - __builtin_amdgcn_readfirstlane(meta[0]);
        int nc = __builtin_amdgcn_readfirstlane(meta[1]) - lo;
        if (nc > nmax) nc = nmax; if (nc < 1) nc = 1;
        if (bid < 4) {                   // vtot[e] = xsum @ Wv + SS*bv
            int ct = bid;
            int e0 = ct * 256 + lane * 4;
            const float* Wp = Wv + (size_t)(wv * 256) * EE + e0;
            const float* xs = xsum + wv * 256;
            float4 a = make_float4(0.f, 0.f, 0.f, 0.f);
#pragma unroll 2
            for (int c = 0; c < 256; c += 4) {
                float4 w0 = *(const float4*)(Wp + (size_t)(c + 0) * EE);
                float4 w1 = *(const float4*)(Wp + (size_t)(c + 1) * EE);
                float4 w2 = *(const float4*)(Wp + (size_t)(c + 2) * EE);
                float4 w3 = *(const float4*)(Wp + (size_t)(c + 3) * EE);
                float4 xv = *(const float4*)(xs + c);
                fma4v(a, xv, w0, w1, w2, w3);
            }
            *(float4*)(lds + wv * 256 + lane * 4) = a;
            __syncthreads();
            if (t < 64) {
                int oc = t * 4;
                float4 s0 = *(float4*)(lds + 0 * 256 + oc);
                float4 s1 = *(float4*)(lds + 1 * 256 + oc);
                float4 s2 = *(float4*)(lds + 2 * 256 + oc);
                float4 s3 = *(float4*)(lds + 3 * 256 + oc);
                float4 bvv = *(const float4*)(bv + ct * 256 + oc);
                float4 s;
                s.x = s0.x + s1.x + s2.x + s3.x + bvv.x * (float)SS;
                s.y = s0.y + s1.y + s2.y + s3.y + bvv.y * (float)SS;
                s.z = s0.z + s1.z + s2.z + s3.z + bvv.z * (float)SS;
                s.w = s0.w + s1.w + s2.w + s3.w + bvv.w * (float)SS;
                *(float4*)(vtot + ct * 256 + oc) = s;
            }
        } else {                         // attention: wave per (r, h)
            int nit = nc * NH;
            float* ql = lds + wv * 256;  // 64 q + 128 sbuf per wave slice
            float* sb = ql + 64;
            for (int it = (bid - 4) * 4 + wv; it < nit; it += (gb - 4) * 4) {
                int r = it >> 4, h = it & 15;
                ql[lane] = Q[(size_t)r * EE + h * DH + lane];
                lgkm_wait();             // cross-lane LDS visibility (same wave)
                const float4* q4 = (const float4*)ql;
                float m = 0.f;           // out-of-seg scores are 0 -> m >= 0
                for (int j = lane; j < nc; j += 64) {
                    const float4* kr = (const float4*)(K + (size_t)j * EE + h * DH);
                    float s = 0.f;
#pragma unroll 4
                    for (int d = 0; d < DH / 4; ++d) {
                        float4 kv = kr[d];
                        float4 qv = q4[d];
                        s += qv.x * kv.x + qv.y * kv.y + qv.z * kv.z + qv.w * kv.w;
                    }
                    sb[j] = s;
                    m = fmaxf(m, s);
                }
                for (int o = 32; o; o >>= 1) m = fmaxf(m, __shfl_xor(m, o, 64));
                float dl = 0.f;
                for (int j = lane; j < nc; j += 64) {
                    float wgt = __expf(sb[j] - m);
                    sb[j] = wgt;
                    dl += wgt;
                }
                for (int o = 32; o; o >>= 1) dl += __shfl_xor(dl, o, 64);
                float em = __expf(-m);
                float denom = dl + (float)(SS - nc) * em;
                lgkm_wait();             // sb written cross-lane before PV reads
                float acc = 0.f, vs = 0.f;
                const float* Vp = V + h * DH + lane;
                int j = 0;
                for (; j + 4 <= nc; j += 4) {
                    float4 wq = *(const float4*)(sb + j);
                    float v0 = Vp[(size_t)(j + 0) * EE];
                    float v1 = Vp[(size_t)(j + 1) * EE];
                    float v2 = Vp[(size_t)(j + 2) * EE];
                    float v3 = Vp[(size_t)(j + 3) * EE];
                    acc += wq.x * v0 + wq.y * v1 + wq.z * v2 + wq.w * v3;
                    vs  += v0 + v1 + v2 + v3;
                }
                for (; j < nc; ++j) {
                    float v0 = Vp[(size_t)j * EE];
                    acc += sb[j] * v0;
                    vs  += v0;
                }
                atomicAdd(&A[h * DH + lane], (acc - vs * em) / denom);
                if (lane == 0) atomicAdd(&Bh[h], em / denom);
            }
        }
    }
    if (phase < 0) cg::this_grid().sync();

    // ================= phase 3: out = bo + (outsum @ Wo) / nc ==============
    if (phase < 0 || phase == 3) {
        if (bid < 4) {
            int nc = __builtin_amdgcn_readfirstlane(meta[1]) -
                     (SS - __builtin_amdgcn_readfirstlane(meta[0]));
            if (nc > nmax) nc = nmax; if (nc < 1) nc = 1;
            int ct = bid;
            {   // outsum[c] = A[c] + vtot[c]*Bh[c>>6] -> lds[0..1023]
                float4 av = ((const float4*)A)[t];
                float4 vv = ((const float4*)vtot)[t];
                float bh = Bh[t >> 4];
                float4 o4;
                o4.x = av.x + vv.x * bh;
                o4.y = av.y + vv.y * bh;
                o4.z = av.z + vv.z * bh;
                o4.w = av.w + vv.w * bh;
                ((float4*)lds)[t] = o4;
            }
            __syncthreads();
            int e0 = ct * 256 + lane * 4;
            const float* Wp = Wo + (size_t)(wv * 256) * EE + e0;
            const float* osp = lds + wv * 256;
            float4 a = make_float4(0.f, 0.f, 0.f, 0.f);
#pragma unroll 2
            for (int c = 0; c < 256; c += 4) {
                float4 w0 = *(const float4*)(Wp + (size_t)(c + 0) * EE);
                float4 w1 = *(const float4*)(Wp + (size_t)(c + 1) * EE);
                float4 w2 = *(const float4*)(Wp + (size_t)(c + 2) * EE);
                float4 w3 = *(const float4*)(Wp + (size_t)(c + 3) * EE);
                float4 ov = *(const float4*)(osp + c);
                fma4v(a, ov, w0, w1, w2, w3);
            }
            *(float4*)(lds + 1024 + wv * 256 + lane * 4) = a;  // red region
            __syncthreads();
            if (t < 64) {
                int oc = t * 4;
                float4 s0 = *(float4*)(lds + 1024 + 0 * 256 + oc);
                float4 s1 = *(float4*)(lds + 1024 + 1 * 256 + oc);
                float4 s2 = *(float4*)(lds + 1024 + 2 * 256 + oc);
                float4 s3 = *(float4*)(lds + 1024 + 3 * 256 + oc);
                float inv = 1.f / (float)nc;
                float4 bov = *(const float4*)(bo + ct * 256 + oc);
                float4 o;
                o.x = bov.x + (s0.x + s1.x + s2.x + s3.x) * inv;
                o.y = bov.y + (s0.y + s1.y + s2.y + s3.y) * inv;
                o.z = bov.z + (s0.z + s1.z + s2.z + s3.z) * inv;
                o.w = bov.w + (s0.w + s1.w + s2.w + s3.w) * inv;
                *(float4*)(out + ct * 256 + oc) = o;
            }
        }
    }
}

extern "C" void kernel_launch(void* const* d_in, const int* in_sizes, int n_in,
                              void* d_out, int out_size, void* d_ws, size_t ws_size,
                              hipStream_t stream) {
    const float* x  = (const float*)d_in[0];
    const int* seg  = (const int*)d_in[1];
    const int* pos  = (const int*)d_in[2];
    const float* Wq = (const float*)d_in[3];
    const float* bq = (const float*)d_in[4];
    const float* Wk = (const float*)d_in[5];
    const float* bk = (const float*)d_in[6];
    const float* Wv = (const float*)d_in[7];
    const float* bv = (const float*)d_in[8];
    const float* Wo = (const float*)d_in[9];
    const float* bo = (const float*)d_in[10];
    float* out = (float*)d_out;

    char* w = (char*)d_ws;
    float* xsum  = (float*)(w + 0);
    float* vtot  = (float*)(w + 4096);
    float* A     = (float*)(w + 8192);
    float* Bh    = (float*)(w + 12288);
    int*   meta  = (int*)(w + 12352);
    float* xpart = (float*)(w + 32768);

    size_t base = 32768 + 64 * EE * sizeof(float);     // 294912
    size_t avail = (ws_size > base) ? ws_size - base : 0;
    int nmax = (int)(avail / (3ull * EE * sizeof(float)));
    if (nmax > NR) nmax = NR;
    if (nmax < 1) nmax = 1;
    float* Q = (float*)(w + base);
    float* K = Q + (size_t)nmax * EE;
    float* V = K + (size_t)nmax * EE;

    hipMemsetAsync(w + 8192, 0, 8192, stream);         // A, Bh, meta

    int phase = -1;
    void* args[] = {(void*)&x,  (void*)&seg, (void*)&pos,
                    (void*)&Wq, (void*)&bq,  (void*)&Wk, (void*)&bk,
                    (void*)&Wv, (void*)&bv,  (void*)&Wo, (void*)&bo,
                    (void*)&xsum, (void*)&vtot, (void*)&A, (void*)&Bh,
                    (void*)&meta, (void*)&xpart, (void*)&Q, (void*)&K,
                    (void*)&V, (void*)&nmax, (void*)&phase, (void*)&out};
    hipError_t rc = hipLaunchCooperativeKernel(mega, dim3(GB), dim3(256),
                                               args, 0, stream);
    if (rc != hipSuccess) {
        // fallback: same kernel, one launch per phase (normal coherence)
        for (int p = 0; p < 4; ++p)
            mega<<<GB, 256, 0, stream>>>(x, seg, pos, Wq, bq, Wk, bk, Wv, bv,
                                         Wo, bo, xsum, vtot, A, Bh, meta,
                                         xpart, Q, K, V, nmax, p, out);
    }
}

// Round 3
// 186.947 us; speedup vs baseline: 1.7035x; 1.7035x over previous
//
#include <hip/hip_runtime.h>

#define SS 2048
#define EE 1024
#define NH 16
#define DH 64
#define NR 128    // max stored segment rows (true count ~Binomial(2048,1/32), mean 64)

// ---- workspace layout (bytes) ----
// 0      : float vtot[1024]              (4 KB)
// 4096   : float A[1024]   (atomic)      } memset 8 KB
// 8192   : float Bh[16]    (atomic)      }
// 16384  : float xpart[64][1024]         (256 KB)
// 278528 : float Q[NR*1024]; K[...]; V[...]

__device__ __forceinline__ void fma4v(float4& a, const float4 xv,
                                      const float4 w0, const float4 w1,
                                      const float4 w2, const float4 w3) {
    a.x += xv.x * w0.x + xv.y * w1.x + xv.z * w2.x + xv.w * w3.x;
    a.y += xv.x * w0.y + xv.y * w1.y + xv.z * w2.y + xv.w * w3.y;
    a.z += xv.x * w0.z + xv.y * w1.z + xv.z * w2.z + xv.w * w3.z;
    a.w += xv.x * w0.w + xv.y * w1.w + xv.z * w2.w + xv.w * w3.w;
}

__device__ __forceinline__ void lgkm_wait() {
    asm volatile("s_waitcnt lgkmcnt(0)" ::: "memory");
}

// Block-uniform segment bounds via redundant in-block scan of seg[2048] (8 KB,
// L2-resident after first block). Returns (lo, hi_excl). 256-thread blocks.
__device__ __forceinline__ int2 seg_bounds(const int* __restrict__ seg,
                                           const int* __restrict__ pos) {
    __shared__ int sb[8];
    int t = threadIdx.x;
    int g = seg[pos[0]];
    int lomin = SS, himax = 0;
    const int4* s4 = (const int4*)seg;
#pragma unroll
    for (int i = t; i < SS / 4; i += 256) {
        int4 v = s4[i];
        int b = i * 4;
        if (v.x == g) { lomin = min(lomin, b);     himax = max(himax, b + 1); }
        if (v.y == g) { lomin = min(lomin, b + 1); himax = max(himax, b + 2); }
        if (v.z == g) { lomin = min(lomin, b + 2); himax = max(himax, b + 3); }
        if (v.w == g) { lomin = min(lomin, b + 3); himax = max(himax, b + 4); }
    }
    for (int o = 32; o; o >>= 1) {
        lomin = min(lomin, __shfl_xor(lomin, o, 64));
        himax = max(himax, __shfl_xor(himax, o, 64));
    }
    if ((t & 63) == 0) { sb[t >> 6] = lomin; sb[4 + (t >> 6)] = himax; }
    __syncthreads();
    return make_int2(min(min(sb[0], sb[1]), min(sb[2], sb[3])),
                     max(max(sb[4], sb[5]), max(sb[6], sb[7])));
}

// D1: z==0 -> x column-sum partials (64 blocks); z==1..3 -> Q/K/V projection.
// Proj block = 4 rows x 256 cols, 4 waves each owning a K-chunk of 256,
// LDS cross-wave reduce, plain float4 stores. Bounds scanned per block.
__global__ void __launch_bounds__(256, 4) k_d1(
    const float* __restrict__ x, const int* __restrict__ seg,
    const int* __restrict__ pos,
    const float* __restrict__ Wq, const float* __restrict__ bq,
    const float* __restrict__ Wk, const float* __restrict__ bk,
    const float* __restrict__ Wv, const float* __restrict__ bv,
    float* __restrict__ xpart,
    float* __restrict__ Q, float* __restrict__ K, float* __restrict__ V,
    int nmax) {
    __shared__ float lds[4096];          // 16 KB reduce buffer
    const int t = threadIdx.x, wv = t >> 6, lane = t & 63;

    if (blockIdx.z == 0) {               // xpart: 64 blocks x 32 rows
        int xb = blockIdx.y * 4 + blockIdx.x;
        if (xb >= 64) return;
        const float4* x4 = (const float4*)x + (size_t)(xb * 32) * 256 + t;
        float4 a = make_float4(0.f, 0.f, 0.f, 0.f);
#pragma unroll 8
        for (int r = 0; r < 32; ++r) {
            float4 v = x4[(size_t)r * 256];
            a.x += v.x; a.y += v.y; a.z += v.z; a.w += v.w;
        }
        ((float4*)(xpart + (size_t)xb * EE))[t] = a;
        return;
    }

    int2 bnd = seg_bounds(seg, pos);
    int lo = bnd.x;
    int nc = bnd.y - lo; if (nc > nmax) nc = nmax; if (nc < 1) nc = 1;
    int r0 = blockIdx.y * 4;
    if (r0 >= nc) return;
    int mat = blockIdx.z - 1;
    const float* W  = mat == 0 ? Wq : mat == 1 ? Wk : Wv;
    const float* bb = mat == 0 ? bq : mat == 1 ? bk : bv;
    float* dst      = mat == 0 ? Q  : mat == 1 ? K  : V;
    int ct = blockIdx.x;
    int e0 = ct * 256 + lane * 4;
    int r1 = r0 + 1 < nc ? r0 + 1 : nc - 1;      // clamp: read valid row,
    int r2 = r0 + 2 < nc ? r0 + 2 : nc - 1;      // result discarded
    int r3 = r0 + 3 < nc ? r0 + 3 : nc - 1;
    const float* xb  = x + (size_t)lo * EE + wv * 256;   // wave-uniform -> s_load
    const float* x0p = xb + (size_t)r0 * EE;
    const float* x1p = xb + (size_t)r1 * EE;
    const float* x2p = xb + (size_t)r2 * EE;
    const float* x3p = xb + (size_t)r3 * EE;
    const float* Wp = W + (size_t)(wv * 256) * EE + e0;
    float4 a0 = make_float4(0.f, 0.f, 0.f, 0.f);
    float4 a1 = a0, a2 = a0, a3 = a0;
#pragma unroll 2
    for (int c = 0; c < 256; c += 4) {
        float4 w0 = *(const float4*)(Wp + (size_t)(c + 0) * EE);
        float4 w1 = *(const float4*)(Wp + (size_t)(c + 1) * EE);
        float4 w2 = *(const float4*)(Wp + (size_t)(c + 2) * EE);
        float4 w3 = *(const float4*)(Wp + (size_t)(c + 3) * EE);
        float4 xv0 = *(const float4*)(x0p + c);
        float4 xv1 = *(const float4*)(x1p + c);
        float4 xv2 = *(const float4*)(x2p + c);
        float4 xv3 = *(const float4*)(x3p + c);
        fma4v(a0, xv0, w0, w1, w2, w3);
        fma4v(a1, xv1, w0, w1, w2, w3);
        fma4v(a2, xv2, w0, w1, w2, w3);
        fma4v(a3, xv3, w0, w1, w2, w3);
    }
    *(float4*)(lds + ((wv << 2) + 0) * 256 + (lane << 2)) = a0;
    *(float4*)(lds + ((wv << 2) + 1) * 256 + (lane << 2)) = a1;
    *(float4*)(lds + ((wv << 2) + 2) * 256 + (lane << 2)) = a2;
    *(float4*)(lds + ((wv << 2) + 3) * 256 + (lane << 2)) = a3;
    __syncthreads();
    // reduce 4 K-chunk partials: thread -> (row=wv, col quad=lane*4)
    int oc = lane << 2;
    float4 s0 = *(float4*)(lds + (0 * 4 + wv) * 256 + oc);
    float4 s1 = *(float4*)(lds + (1 * 4 + wv) * 256 + oc);
    float4 s2 = *(float4*)(lds + (2 * 4 + wv) * 256 + oc);
    float4 s3 = *(float4*)(lds + (3 * 4 + wv) * 256 + oc);
    float4 bbv = *(const float4*)(bb + ct * 256 + oc);
    float4 s;
    s.x = s0.x + s1.x + s2.x + s3.x + bbv.x;
    s.y = s0.y + s1.y + s2.y + s3.y + bbv.y;
    s.z = s0.z + s1.z + s2.z + s3.z + bbv.z;
    s.w = s0.w + s1.w + s2.w + s3.w + bbv.w;
    int gr = r0 + wv;
    if (gr < nc)
        *(float4*)(dst + (size_t)gr * EE + ct * 256 + oc) = s;
}

// D2: blocks 0-3 -> vtot = (xsum @ Wv) + SS*bv (xpart reduced in-LDS);
//     blocks 4+  -> attention, one wave per (row r, head h), A/Bh atomics.
__global__ void __launch_bounds__(256, 4) k_d2(
    const int* __restrict__ seg, const int* __restrict__ pos,
    const float* __restrict__ Wv, const float* __restrict__ bv,
    const float* __restrict__ xpart,
    const float* __restrict__ Q, const float* __restrict__ K,
    const float* __restrict__ V,
    float* __restrict__ vtot, float* __restrict__ A, float* __restrict__ Bh,
    int nmax) {
    __shared__ float lds[2048];
    const int t = threadIdx.x, wv = t >> 6, lane = t & 63;
    const int bid = blockIdx.x, gb = gridDim.x;

    if (bid < 4) {                       // vtot GEMV
        float4 a = make_float4(0.f, 0.f, 0.f, 0.f);
        const float4* xp4 = (const float4*)xpart + t;
#pragma unroll 8
        for (int b = 0; b < 64; ++b) {
            float4 v = xp4[(size_t)b * 256];
            a.x += v.x; a.y += v.y; a.z += v.z; a.w += v.w;
        }
        ((float4*)lds)[t] = a;           // xsum in lds[0..1023]
        __syncthreads();
        int ct = bid;
        int e0 = ct * 256 + lane * 4;
        const float* Wp = Wv + (size_t)(wv * 256) * EE + e0;
        const float* xs = lds + wv * 256;
        float4 acc = make_float4(0.f, 0.f, 0.f, 0.f);
#pragma unroll 2
        for (int c = 0; c < 256; c += 4) {
            float4 w0 = *(const float4*)(Wp + (size_t)(c + 0) * EE);
            float4 w1 = *(const float4*)(Wp + (size_t)(c + 1) * EE);
            float4 w2 = *(const float4*)(Wp + (size_t)(c + 2) * EE);
            float4 w3 = *(const float4*)(Wp + (size_t)(c + 3) * EE);
            float4 xv = *(const float4*)(xs + c);
            fma4v(acc, xv, w0, w1, w2, w3);
        }
        *(float4*)(lds + 1024 + wv * 256 + lane * 4) = acc;
        __syncthreads();
        if (t < 64) {
            int oc = t * 4;
            float4 s0 = *(float4*)(lds + 1024 + 0 * 256 + oc);
            float4 s1 = *(float4*)(lds + 1024 + 1 * 256 + oc);
            float4 s2 = *(float4*)(lds + 1024 + 2 * 256 + oc);
            float4 s3 = *(float4*)(lds + 1024 + 3 * 256 + oc);
            float4 bvv = *(const float4*)(bv + ct * 256 + oc);
            float4 s;
            s.x = s0.x + s1.x + s2.x + s3.x + bvv.x * (float)SS;
            s.y = s0.y + s1.y + s2.y + s3.y + bvv.y * (float)SS;
            s.z = s0.z + s1.z + s2.z + s3.z + bvv.z * (float)SS;
            s.w = s0.w + s1.w + s2.w + s3.w + bvv.w * (float)SS;
            *(float4*)(vtot + ct * 256 + oc) = s;
        }
        return;
    }

    int2 bnd = seg_bounds(seg, pos);
    int nc = bnd.y - bnd.x; if (nc > nmax) nc = nmax; if (nc < 1) nc = 1;
    int nit = nc * NH;
    float* ql = lds + wv * 512;          // per-wave slice: 64 q + 128 sbuf
    float* sb = ql + 64;
    for (int it = (bid - 4) * 4 + wv; it < nit; it += (gb - 4) * 4) {
        int r = it >> 4, h = it & 15;
        ql[lane] = Q[(size_t)r * EE + h * DH + lane];
        lgkm_wait();                     // cross-lane LDS visibility (same wave)
        const float4* q4 = (const float4*)ql;
        float m = 0.f;                   // out-of-seg scores are 0 -> m >= 0
        for (int j = lane; j < nc; j += 64) {
            const float4* kr = (const float4*)(K + (size_t)j * EE + h * DH);
            float s = 0.f;
#pragma unroll 4
            for (int d = 0; d < DH / 4; ++d) {
                float4 kv = kr[d];
                float4 qv = q4[d];
                s += qv.x * kv.x + qv.y * kv.y + qv.z * kv.z + qv.w * kv.w;
            }
            sb[j] = s;
            m = fmaxf(m, s);
        }
        for (int o = 32; o; o >>= 1) m = fmaxf(m, __shfl_xor(m, o, 64));
        float dl = 0.f;
        for (int j = lane; j < nc; j += 64) {
            float wgt = __expf(sb[j] - m);
            sb[j] = wgt;
            dl += wgt;
        }
        for (int o = 32; o; o >>= 1) dl += __shfl_xor(dl, o, 64);
        float em = __expf(-m);
        float denom = dl + (float)(SS - nc) * em;
        lgkm_wait();                     // sb written cross-lane before PV reads
        float acc = 0.f, vs = 0.f;
        const float* Vp = V + h * DH + lane;
        int j = 0;
        for (; j + 4 <= nc; j += 4) {
            float4 wq = *(const float4*)(sb + j);
            float v0 = Vp[(size_t)(j + 0) * EE];
            float v1 = Vp[(size_t)(j + 1) * EE];
            float v2 = Vp[(size_t)(j + 2) * EE];
            float v3 = Vp[(size_t)(j + 3) * EE];
            acc += wq.x * v0 + wq.y * v1 + wq.z * v2 + wq.w * v3;
            vs  += v0 + v1 + v2 + v3;
        }
        for (; j < nc; ++j) {
            float v0 = Vp[(size_t)j * EE];
            acc += sb[j] * v0;
            vs  += v0;
        }
        atomicAdd(&A[h * DH + lane], (acc - vs * em) / denom);
        if (lane == 0) atomicAdd(&Bh[h], em / denom);
    }
}

// D3: out = bo + ((A + vtot*Bh) @ Wo) / nc.  4 blocks x 256-col stripes.
__global__ void __launch_bounds__(256, 2) k_d3(
    const int* __restrict__ seg, const int* __restrict__ pos,
    const float* __restrict__ Wo, const float* __restrict__ bo,
    const float* __restrict__ vtot, const float* __restrict__ A,
    const float* __restrict__ Bh, int nmax, float* __restrict__ out) {
    __shared__ float lds[2048];
    const int t = threadIdx.x, wv = t >> 6, lane = t & 63;
    int2 bnd = seg_bounds(seg, pos);
    int nc = bnd.y - bnd.x; if (nc > nmax) nc = nmax; if (nc < 1) nc = 1;
    {   // outsum[c] = A[c] + vtot[c]*Bh[c>>6] -> lds[0..1023]
        float4 av = ((const float4*)A)[t];
        float4 vv = ((const float4*)vtot)[t];
        float bh = Bh[t >> 4];
        float4 o4;
        o4.x = av.x + vv.x * bh;
        o4.y = av.y + vv.y * bh;
        o4.z = av.z + vv.z * bh;
        o4.w = av.w + vv.w * bh;
        ((float4*)lds)[t] = o4;
    }
    __syncthreads();
    int ct = blockIdx.x;
    int e0 = ct * 256 + lane * 4;
    const float* Wp = Wo + (size_t)(wv * 256) * EE + e0;
    const float* osp = lds + wv * 256;
    float4 a = make_float4(0.f, 0.f, 0.f, 0.f);
#pragma unroll 2
    for (int c = 0; c < 256; c += 4) {
        float4 w0 = *(const float4*)(Wp + (size_t)(c + 0) * EE);
        float4 w1 = *(const float4*)(Wp + (size_t)(c + 1) * EE);
        float4 w2 = *(const float4*)(Wp + (size_t)(c + 2) * EE);
        float4 w3 = *(const float4*)(Wp + (size_t)(c + 3) * EE);
        float4 ov = *(const float4*)(osp + c);
        fma4v(a, ov, w0, w1, w2, w3);
    }
    *(float4*)(lds + 1024 + wv * 256 + lane * 4) = a;
    __syncthreads();
    if (t < 64) {
        int oc = t * 4;
        float4 s0 = *(float4*)(lds + 1024 + 0 * 256 + oc);
        float4 s1 = *(float4*)(lds + 1024 + 1 * 256 + oc);
        float4 s2 = *(float4*)(lds + 1024 + 2 * 256 + oc);
        float4 s3 = *(float4*)(lds + 1024 + 3 * 256 + oc);
        float inv = 1.f / (float)nc;
        float4 bov = *(const float4*)(bo + ct * 256 + oc);
        float4 o;
        o.x = bov.x + (s0.x + s1.x + s2.x + s3.x) * inv;
        o.y = bov.y + (s0.y + s1.y + s2.y + s3.y) * inv;
        o.z = bov.z + (s0.z + s1.z + s2.z + s3.z) * inv;
        o.w = bov.w + (s0.w + s1.w + s2.w + s3.w) * inv;
        *(float4*)(out + ct * 256 + oc) = o;
    }
}

extern "C" void kernel_launch(void* const* d_in, const int* in_sizes, int n_in,
                              void* d_out, int out_size, void* d_ws, size_t ws_size,
                              hipStream_t stream) {
    const float* x  = (const float*)d_in[0];
    const int* seg  = (const int*)d_in[1];
    const int* pos  = (const int*)d_in[2];
    const float* Wq = (const float*)d_in[3];
    const float* bq = (const float*)d_in[4];
    const float* Wk = (const float*)d_in[5];
    const float* bk = (const float*)d_in[6];
    const float* Wv = (const float*)d_in[7];
    const float* bv = (const float*)d_in[8];
    const float* Wo = (const float*)d_in[9];
    const float* bo = (const float*)d_in[10];
    float* out = (float*)d_out;

    char* w = (char*)d_ws;
    float* vtot  = (float*)(w + 0);
    float* A     = (float*)(w + 4096);
    float* Bh    = (float*)(w + 8192);
    float* xpart = (float*)(w + 16384);

    size_t base = 16384 + 64 * EE * sizeof(float);     // 278528
    size_t avail = (ws_size > base) ? ws_size - base : 0;
    int nmax = (int)(avail / (3ull * EE * sizeof(float)));
    if (nmax > NR) nmax = NR;
    if (nmax < 1) nmax = 1;
    float* Q = (float*)(w + base);
    float* K = Q + (size_t)nmax * EE;
    float* V = K + (size_t)nmax * EE;

    int RT = (nmax + 3) / 4;
    int RY = RT > 16 ? RT : 16;          // y-extent must cover 64 xpart blocks

    hipMemsetAsync(w + 4096, 0, 8192, stream);         // A, Bh
    k_d1<<<dim3(4, RY, 4), 256, 0, stream>>>(
        x, seg, pos, Wq, bq, Wk, bk, Wv, bv, xpart, Q, K, V, nmax);
    k_d2<<<260, 256, 0, stream>>>(
        seg, pos, Wv, bv, xpart, Q, K, V, vtot, A, Bh, nmax);
    k_d3<<<4, 256, 0, stream>>>(seg, pos, Wo, bo, vtot, A, Bh, nmax, out);
}